// Round 8
// baseline (414.308 us; speedup 1.0000x reference)
//
#include <hip/hip_runtime.h>
#include <math.h>

#define NN   50000
#define EE   800000
#define EF   850000   // EE + NN self loops
#define HH   128
#define FE   16
#define LATD 64
#define MAXNN 200

#define ADJ_TOT   10000000   // NN*MAXNN
#define NODES_TOT 6400000    // NN*HH
#define OUT_TOT   16400000   // ADJ_TOT + NODES_TOT
#define MU_OFF    16400000
#define LV_OFF    16400064

#define GEMMBLOCKS 782       // (NN+63)/64
#define DEGBLOCKS  782       // ceil(EE/1024): 4 edges/thread
#define NBSCAN     49        // (NN+1023)/1024

typedef __attribute__((ext_vector_type(8))) short bf16x8;
typedef __attribute__((ext_vector_type(4))) float f32x4;
typedef __attribute__((ext_vector_type(2))) float f32x2;

__device__ __forceinline__ unsigned short f2bf(float f){
  unsigned int u = __float_as_uint(f);
  unsigned int r = (u + 0x7FFFu + ((u>>16)&1u)) >> 16;   // RNE
  return (unsigned short)r;
}
__device__ __forceinline__ float bf2f(unsigned short h){
  return __uint_as_float(((unsigned int)h)<<16);
}

// ---------------- prep: zero ideg/hgsum + wa fold + W transpose/pack ----------------
__global__ __launch_bounds__(256) void kprep(int* ideg, float* hgsum,
                       const float* We1, const float* ae1, const float* We2, const float* ae2,
                       float* wa1, float* wa2,
                       const float* W1, const float* W2,
                       unsigned short* Wp1, unsigned short* Wp2){
  int i = blockIdx.x*256 + threadIdx.x;
  if(i < NN) ideg[i]=0;
  if(i < HH) hgsum[i]=0.f;
  if(i < FE){
    float s1=0.f, s2=0.f;
    for(int j=0;j<HH;j++){ s1 += We1[i*HH+j]*ae1[j]; s2 += We2[i*HH+j]*ae2[j]; }
    wa1[i]=s1; wa2[i]=s2;
  }
  if(i < HH*HH){
    int n = i >> 7, k = i & 127;
    Wp1[i] = f2bf(W1[k*HH + n]);
    Wp2[i] = f2bf(W2[k*HH + n]);
  }
}

// ---------------- MFMA GEMM body: A8 = fp8( h @ W ), fused asrc/adst ----------------
__device__ __forceinline__ void gemm_body(int bid, int tid, const void* __restrict__ hin, int h_is_fp32,
    const unsigned short* __restrict__ Wp,
    const float* __restrict__ atts, const float* __restrict__ attd,
    unsigned char* __restrict__ A8, float* __restrict__ asrc, float* __restrict__ adst){
  int lane = tid & 63;
  int wid  = tid >> 6;
  int l = lane & 15, q = lane >> 4;
  int r0 = bid*64 + wid*16;
  if(r0 >= NN) return;
  const unsigned short* hb = (const unsigned short*)hin;
  const float*          hf = (const float*)hin;
  int row = r0 + l;

  // prefetch ALL A fragments first
  bf16x8 afr[4];
  if(h_is_fp32){
    float4 u[8];
    #pragma unroll
    for(int kb=0;kb<4;kb++){
      const float* p = hf + (size_t)row*HH + kb*32 + q*8;
      u[kb*2]   = *(const float4*)(p);
      u[kb*2+1] = *(const float4*)(p+4);
    }
    #pragma unroll
    for(int kb=0;kb<4;kb++){
      afr[kb][0]=(short)f2bf(u[kb*2].x);   afr[kb][1]=(short)f2bf(u[kb*2].y);
      afr[kb][2]=(short)f2bf(u[kb*2].z);   afr[kb][3]=(short)f2bf(u[kb*2].w);
      afr[kb][4]=(short)f2bf(u[kb*2+1].x); afr[kb][5]=(short)f2bf(u[kb*2+1].y);
      afr[kb][6]=(short)f2bf(u[kb*2+1].z); afr[kb][7]=(short)f2bf(u[kb*2+1].w);
    }
  } else {
    #pragma unroll
    for(int kb=0;kb<4;kb++)
      afr[kb] = *(const bf16x8*)(hb + (size_t)row*HH + kb*32 + q*8);
  }

  f32x4 acc[8];
  #pragma unroll
  for(int t=0;t<8;t++) acc[t]=(f32x4){0.f,0.f,0.f,0.f};

  #pragma unroll
  for(int kb=0;kb<4;kb++){
    #pragma unroll
    for(int t=0;t<8;t++){
      bf16x8 b = *(const bf16x8*)(Wp + (size_t)(t*16+l)*HH + kb*32 + q*8);
      acc[t] = __builtin_amdgcn_mfma_f32_16x16x32_bf16(afr[kb], b, acc[t], 0,0,0);
    }
  }

  float av[8], dv[8];
  #pragma unroll
  for(int t=0;t<8;t++){ av[t]=atts[t*16+l]; dv[t]=attd[t*16+l]; }
  #pragma unroll
  for(int reg=0;reg<4;reg++){
    float ps=0.f, pd=0.f;
    #pragma unroll
    for(int t=0;t<8;t++){ ps+=acc[t][reg]*av[t]; pd+=acc[t][reg]*dv[t]; }
    #pragma unroll
    for(int m=8;m>=1;m>>=1){ ps+=__shfl_xor(ps,m,16); pd+=__shfl_xor(pd,m,16); }
    if(l==0){ int R=r0+q*4+reg; asrc[R]=ps; adst[R]=pd; }
  }
  #pragma unroll
  for(int t=0;t<8;t++)
    #pragma unroll
    for(int reg=0;reg<4;reg++){
      int pk = __builtin_amdgcn_cvt_pk_fp8_f32(acc[t][reg], 0.f, 0, false);
      A8[(size_t)(r0+q*4+reg)*HH + t*16 + l] = (unsigned char)(pk & 0xFF);
    }
}

__global__ __launch_bounds__(256) void kgemm3(const void* __restrict__ hin, int h_is_fp32,
    const unsigned short* __restrict__ Wp,
    const float* __restrict__ atts, const float* __restrict__ attd,
    unsigned char* __restrict__ A8, float* __restrict__ asrc, float* __restrict__ adst){
  gemm_body(blockIdx.x, threadIdx.x, hin, h_is_fp32, Wp, atts, attd, A8, asrc, adst);
}

// gemm L1 (blocks [0,GEMMBLOCKS)) + degree/erank atomics (4 edges/thread, rest).
__global__ __launch_bounds__(256) void kdeggemm(
    const int* __restrict__ ei, int* ideg, unsigned short* __restrict__ erank,
    const void* __restrict__ hin, int h_is_fp32,
    const unsigned short* __restrict__ Wp,
    const float* __restrict__ atts, const float* __restrict__ attd,
    unsigned char* __restrict__ A8, float* __restrict__ asrc, float* __restrict__ adst){
  if(blockIdx.x < GEMMBLOCKS){
    gemm_body(blockIdx.x, threadIdx.x, hin, h_is_fp32, Wp, atts, attd, A8, asrc, adst);
  } else {
    int e0 = ((blockIdx.x - GEMMBLOCKS)*256 + threadIdx.x)*4;
    if(e0 + 3 < EE){
      int4 d4 = *(const int4*)(ei + EE + e0);
      unsigned short r0 = (unsigned short)atomicAdd(&ideg[d4.x], 1);
      unsigned short r1 = (unsigned short)atomicAdd(&ideg[d4.y], 1);
      unsigned short r2 = (unsigned short)atomicAdd(&ideg[d4.z], 1);
      unsigned short r3 = (unsigned short)atomicAdd(&ideg[d4.w], 1);
      ushort4 rr; rr.x=r0; rr.y=r1; rr.z=r2; rr.w=r3;
      *(ushort4*)(erank + e0) = rr;
    } else {
      for(int j=0;j<4;j++)
        if(e0+j < EE) erank[e0+j] = (unsigned short)atomicAdd(&ideg[ei[EE+e0+j]], 1);
    }
  }
}

// ---------------- exclusive scan of rowlen = ideg+1 ----------------
__global__ void kscan1(const int* __restrict__ ideg, int* rowstart, int* blocksum){
  __shared__ int sd[1024];
  int t=threadIdx.x; int i=blockIdx.x*1024+t;
  int v = (i<NN)? (ideg[i]+1) : 0;
  sd[t]=v; __syncthreads();
  for(int off=1; off<1024; off<<=1){
    int x = (t>=off)? sd[t-off] : 0;
    __syncthreads();
    sd[t] += x;
    __syncthreads();
  }
  if(i<NN) rowstart[i] = sd[t]-v;
  if(t==1023) blocksum[blockIdx.x]=sd[1023];
}
// scan3 with inline block-sum scan (in-place +=, writes rowstart[NN])
__global__ __launch_bounds__(256) void kscan3i(int* rowstart, const int* __restrict__ blocksum){
  __shared__ int bo[64];
  int t = threadIdx.x;
  if(t < 64){
    int v = (t < NBSCAN)? blocksum[t] : 0;
    int inc = v;
    #pragma unroll
    for(int off=1; off<64; off<<=1){
      int x = __shfl_up(inc, off);
      if(t>=off) inc += x;
    }
    bo[t] = inc - v;           // exclusive; bo[NBSCAN] = total
  }
  __syncthreads();
  int i = blockIdx.x*256 + t;
  if(i<NN) rowstart[i] += bo[i>>10];
  if(i==0) rowstart[NN] = bo[NBSCAN];
}

// ---------------- CSR scatter: 2 edges/thread, packed 8B entries, NO atomic ---------
__device__ __forceinline__ unsigned etpack(const float4* a4,
                         const float* __restrict__ wa1, const float* __restrict__ wa2){
  float4 v0=a4[0], v1=a4[1], v2=a4[2], v3=a4[3];
  float va[16]={v0.x,v0.y,v0.z,v0.w, v1.x,v1.y,v1.z,v1.w,
                v2.x,v2.y,v2.z,v2.w, v3.x,v3.y,v3.z,v3.w};
  float d1=0.f,d2=0.f;
  #pragma unroll
  for(int f=0;f<FE;f++){ d1+=va[f]*wa1[f]; d2+=va[f]*wa2[f]; }
  return (unsigned)f2bf(d1) | ((unsigned)f2bf(d2)<<16);
}
__global__ __launch_bounds__(256) void kscatter(const int* __restrict__ ei, const float* __restrict__ ea,
                         const float* __restrict__ wa1, const float* __restrict__ wa2,
                         const int* __restrict__ rowstart, const unsigned short* __restrict__ erank,
                         uint2* __restrict__ csr){
  int e0 = (blockIdx.x*256 + threadIdx.x)*2;
  if(e0>=EE) return;
  int sA=ei[e0],    sB=ei[e0+1];
  int dA=ei[EE+e0], dB=ei[EE+e0+1];
  int rA=(int)erank[e0], rB=(int)erank[e0+1];
  int pA=rowstart[dA]+rA, pB=rowstart[dB]+rB;
  const float4* a4 = (const float4*)(ea + (size_t)e0*FE);
  unsigned yA = etpack(a4,   wa1, wa2);
  unsigned yB = etpack(a4+4, wa1, wa2);
  uint2 enA; enA.x=(unsigned)sA; enA.y=yA;
  uint2 enB; enB.x=(unsigned)sB; enB.y=yB;
  csr[pA]=enA; csr[pB]=enB;
}

// ---------------- GAT softmax-aggregate: ONE WAVE per dst node ----------------------
// mode 0 (layer 1): et = lo half; computes self-loop et means (lo AND hi) via shfl
//   chains and WRITES the packed self entry to csr[base+len-1] for layer 2.
// mode 1 (layer 2): self entry already in csr -> uniform read, NO ets chain.
// Quad gather: lane=(qq,lq); batch-0 loads issued before softmax chains.
__global__ __launch_bounds__(256) void kgat(const unsigned char* __restrict__ A8,
    const float* __restrict__ asrc, const float* __restrict__ adst,
    const int* __restrict__ rowstart, uint2* __restrict__ csr,
    int mode, const float* __restrict__ bias,
    float* __restrict__ alphabuf, int* __restrict__ srcbuf,
    unsigned short* __restrict__ Bout){
  int lane = threadIdx.x & 63;
  int wid  = threadIdx.x >> 6;
  int i = blockIdx.x*4 + wid;
  if(i >= NN) return;
  int base = rowstart[i];
  int len  = rowstart[i+1]-base;      // deg + 1 (self)
  float adi = adst[i];
  int lq = lane & 15;                 // feature chunk (feats lq*8 .. lq*8+7)
  int qq = lane >> 4;                 // edge sub-slot 0..3
  float av[8];
  #pragma unroll
  for(int j=0;j<8;j++) av[j]=0.f;

  if(__builtin_expect(len <= 64, 1)){
    int P4 = (len+3)>>2;               // 1..16 quad slots
    // ---- load csr entry; finalize s for all lanes ----
    int nread = mode ? len : len-1;
    int s = i; float etlo = 0.f, ethi = 0.f;
    if(lane < nread){
      uint2 en = csr[base+lane];
      s = (int)en.x;
      etlo = bf2f((unsigned short)(en.y & 0xFFFFu));
      ethi = bf2f((unsigned short)(en.y >> 16));
    }
    float et = mode ? ethi : etlo;
    // ---- prefetch gather batch 0 (addresses need only s) ----
    int skv0[6];
    #pragma unroll
    for(int j=0;j<6;j++) skv0[j] = (j<P4) ? __shfl(s, 4*j+qq) : i;
    unsigned ux[6], uy[6];
    #pragma unroll
    for(int j=0;j<6;j++){
      uint2 u = *(const uint2*)(A8 + (size_t)skv0[j]*HH + lq*8);
      ux[j]=u.x; uy[j]=u.y;
    }
    // ---- mode 0: self-loop et means (both halves), write self entry ----
    if(!mode){
      float e1 = (lane < len-1) ? etlo : 0.f;
      float e2 = (lane < len-1) ? ethi : 0.f;
      #pragma unroll
      for(int mk=32;mk>=1;mk>>=1){ e1 += __shfl_xor(e1,mk); e2 += __shfl_xor(e2,mk); }
      float dg = fmaxf((float)(len-1), 1.f);
      float m1 = e1/dg, m2 = e2/dg;
      if(lane == len-1){
        et = m1;
        uint2 se; se.x=(unsigned)i;
        se.y=(unsigned)f2bf(m1) | ((unsigned)f2bf(m2)<<16);
        csr[base+len-1] = se;
      }
    }
    // ---- softmax ----
    float a = -1e30f;
    if(lane < len){
      a = asrc[s] + adi + et;
      a = fmaxf(a, 0.2f*a);            // leaky_relu 0.2
    }
    float m = a;
    #pragma unroll
    for(int mk=32;mk>=1;mk>>=1) m = fmaxf(m, __shfl_xor(m,mk));
    float ex = (lane<len) ? __expf(a-m) : 0.f;
    float sm = ex;
    #pragma unroll
    for(int mk=32;mk>=1;mk>>=1) sm += __shfl_xor(sm,mk);
    ex *= __builtin_amdgcn_rcpf(sm);   // fold 1/den into the weight

    // ---- consume batch 0 ----
    float w0[6];
    #pragma unroll
    for(int j=0;j<6;j++) w0[j] = (j<P4) ? __shfl(ex, 4*j+qq) : 0.f;
    #pragma unroll
    for(int j=0;j<6;j++){
      f32x2 v;
      v=__builtin_amdgcn_cvt_pk_f32_fp8((int)ux[j],false); av[0]+=w0[j]*v[0]; av[1]+=w0[j]*v[1];
      v=__builtin_amdgcn_cvt_pk_f32_fp8((int)ux[j],true ); av[2]+=w0[j]*v[0]; av[3]+=w0[j]*v[1];
      v=__builtin_amdgcn_cvt_pk_f32_fp8((int)uy[j],false); av[4]+=w0[j]*v[0]; av[5]+=w0[j]*v[1];
      v=__builtin_amdgcn_cvt_pk_f32_fp8((int)uy[j],true ); av[6]+=w0[j]*v[0]; av[7]+=w0[j]*v[1];
    }
    // ---- remaining batches (len > 24 only) ----
    for(int t0=6; t0<P4; t0+=6){
      int skv[6]; float w[6];
      #pragma unroll
      for(int j=0;j<6;j++){
        if(t0+j < P4){
          int idx = 4*(t0+j) + qq;     // <= 63
          skv[j] = __shfl(s, idx);
          w[j]   = __shfl(ex, idx);
        } else { skv[j] = i; w[j] = 0.f; }
      }
      unsigned vx[6], vy[6];
      #pragma unroll
      for(int j=0;j<6;j++){
        uint2 u = *(const uint2*)(A8 + (size_t)skv[j]*HH + lq*8);
        vx[j]=u.x; vy[j]=u.y;
      }
      #pragma unroll
      for(int j=0;j<6;j++){
        f32x2 v;
        v=__builtin_amdgcn_cvt_pk_f32_fp8((int)vx[j],false); av[0]+=w[j]*v[0]; av[1]+=w[j]*v[1];
        v=__builtin_amdgcn_cvt_pk_f32_fp8((int)vx[j],true ); av[2]+=w[j]*v[0]; av[3]+=w[j]*v[1];
        v=__builtin_amdgcn_cvt_pk_f32_fp8((int)vy[j],false); av[4]+=w[j]*v[0]; av[5]+=w[j]*v[1];
        v=__builtin_amdgcn_cvt_pk_f32_fp8((int)vy[j],true ); av[6]+=w[j]*v[0]; av[7]+=w[j]*v[1];
      }
    }
  } else {
    // rare fallback: strided two-pass with global spill
    int deg = len-1;
    int lim = mode ? len : deg;
    float lm = -1e30f, e1 = 0.f, e2 = 0.f;
    for(int k=lane;k<lim;k+=64){
      uint2 en = csr[base+k];
      int sr = (int)en.x;
      float lo = bf2f((unsigned short)(en.y & 0xFFFFu));
      float hi = bf2f((unsigned short)(en.y >> 16));
      float etv = mode ? hi : lo;
      if(!mode){ e1 += lo; e2 += hi; }
      float a = asrc[sr] + adi + etv;
      a = fmaxf(a, 0.2f*a);
      alphabuf[base+k]=a; srcbuf[base+k]=sr;
      lm = fmaxf(lm,a);
    }
    #pragma unroll
    for(int mk=32;mk>=1;mk>>=1){
      e1 += __shfl_xor(e1,mk);
      e2 += __shfl_xor(e2,mk);
      lm  = fmaxf(lm, __shfl_xor(lm,mk));
    }
    float aself = 0.f;
    if(!mode){
      float m1 = e1/(float)deg, m2 = e2/(float)deg;
      aself = asrc[i] + adi + m1;
      aself = fmaxf(aself, 0.2f*aself);
      lm = fmaxf(lm, aself);
      if(lane==0){
        uint2 se; se.x=(unsigned)i;
        se.y=(unsigned)f2bf(m1) | ((unsigned)f2bf(m2)<<16);
        csr[base+deg] = se;
      }
    }
    float ls=0.f;
    for(int k=lane;k<len;k+=64){
      float a;
      if(mode) a = alphabuf[base+k];
      else     a = (k<deg)? alphabuf[base+k] : aself;
      float e_ = __expf(a-lm);
      alphabuf[base+k]=e_;
      ls += e_;
    }
    #pragma unroll
    for(int mk=32;mk>=1;mk>>=1) ls += __shfl_xor(ls,mk);
    float inv = 1.f/ls;
    int lim2 = mode ? len : deg;
    int P4 = (len+3)>>2;
    for(int t=0;t<P4;t++){
      int k = 4*t + qq;
      int sk = i; float wk = 0.f;
      if(k<len){
        sk = (k<lim2)? srcbuf[base+k] : i;
        wk = alphabuf[base+k]*inv;
      }
      uint2 u = *(const uint2*)(A8 + (size_t)sk*HH + lq*8);
      f32x2 v;
      v=__builtin_amdgcn_cvt_pk_f32_fp8((int)u.x,false); av[0]+=wk*v[0]; av[1]+=wk*v[1];
      v=__builtin_amdgcn_cvt_pk_f32_fp8((int)u.x,true ); av[2]+=wk*v[0]; av[3]+=wk*v[1];
      v=__builtin_amdgcn_cvt_pk_f32_fp8((int)u.y,false); av[4]+=wk*v[0]; av[5]+=wk*v[1];
      v=__builtin_amdgcn_cvt_pk_f32_fp8((int)u.y,true ); av[6]+=wk*v[0]; av[7]+=wk*v[1];
    }
  }

  // ---- fold edge sub-slots (lanes with same lq hold same features) ----
  #pragma unroll
  for(int j=0;j<8;j++){
    av[j] += __shfl_xor(av[j],16);
    av[j] += __shfl_xor(av[j],32);
  }
  // ---- epilogue: 16 lanes store uint4 = full 256B bf16 row ----
  if(qq==0){
    const float4* bp = (const float4*)(bias + lq*8);
    float4 b0=bp[0], b1=bp[1];
    float o0=fmaxf(av[0]+b0.x,0.f), o1=fmaxf(av[1]+b0.y,0.f);
    float o2=fmaxf(av[2]+b0.z,0.f), o3=fmaxf(av[3]+b0.w,0.f);
    float o4=fmaxf(av[4]+b1.x,0.f), o5=fmaxf(av[5]+b1.y,0.f);
    float o6=fmaxf(av[6]+b1.z,0.f), o7=fmaxf(av[7]+b1.w,0.f);
    uint4 ov;
    ov.x=(unsigned)f2bf(o0)|((unsigned)f2bf(o1)<<16);
    ov.y=(unsigned)f2bf(o2)|((unsigned)f2bf(o3)<<16);
    ov.z=(unsigned)f2bf(o4)|((unsigned)f2bf(o5)<<16);
    ov.w=(unsigned)f2bf(o6)|((unsigned)f2bf(o7)<<16);
    *(uint4*)(Bout + (size_t)i*HH + lq*8) = ov;
  }
}

// ---------------- column mean (bf16 input): grid-strided, 512 blocks ----------------
__global__ __launch_bounds__(256) void khg(const unsigned short* __restrict__ B, float* hgsum){
  int f = threadIdx.x & 127;      // column
  int half = threadIdx.x >> 7;    // 0/1
  float s=0.f;
  for(int i = blockIdx.x*2+half; i < NN; i += gridDim.x*2)
    s += bf2f(B[(size_t)i*HH + f]);
  __shared__ float sd[256];
  sd[threadIdx.x]=s; __syncthreads();
  if(half==0) atomicAdd(&hgsum[f], sd[threadIdx.x]+sd[threadIdx.x+128]);
}

// ---------------- tiny decoder, single block ----------------
__global__ __launch_bounds__(256) void kdec(const float* __restrict__ hgsum, const float* __restrict__ eps,
   const float* muW,const float* mub,const float* lvW,const float* lvb,
   const float* decW,const float* decb,
   const float* aW1,const float* ab1,const float* aW2,const float* ab2,
   const float* nW1,const float* nb1,const float* nW2,const float* nb2,
   float* out, float* rowadj, float* rownodes){
  __shared__ float hg[HH], z[LATD], hd[HH], t1[HH], t2[HH];
  int t=threadIdx.x;
  if(t<HH) hg[t]=hgsum[t]*(1.0f/NN);
  __syncthreads();
  if(t<LATD){
    float mu=mub[t], lv=lvb[t];
    #pragma unroll 8
    for(int k=0;k<HH;k++){ mu += hg[k]*muW[k*LATD+t]; lv += hg[k]*lvW[k*LATD+t]; }
    out[MU_OFF+t]=mu; out[LV_OFF+t]=lv;
    z[t]=mu + eps[t]*expf(0.5f*lv);
  }
  __syncthreads();
  if(t<HH){
    float a=decb[t];
    #pragma unroll 8
    for(int k=0;k<LATD;k++) a += z[k]*decW[k*HH+t];
    hd[t]=fmaxf(a,0.f);
  }
  __syncthreads();
  if(t<HH){
    float a=ab1[t];
    #pragma unroll 8
    for(int k=0;k<HH;k++) a += hd[k]*aW1[k*HH+t];
    t1[t]=fmaxf(a,0.f);
  } else {
    int j=t-HH;
    float a=nb1[j];
    #pragma unroll 8
    for(int k=0;k<HH;k++) a += hd[k]*nW1[k*HH+j];
    t2[j]=fmaxf(a,0.f);
  }
  __syncthreads();
  for(int j=t;j<MAXNN;j+=256){
    float a=ab2[j];
    #pragma unroll 8
    for(int k=0;k<HH;k++) a += t1[k]*aW2[k*MAXNN+j];
    rowadj[j]=a;
  }
  if(t<HH){
    float a=nb2[t];
    #pragma unroll 8
    for(int k=0;k<HH;k++) a += t2[k]*nW2[k*HH+t];
    rownodes[t]=a;
  }
}

// ---------------- broadcast the two decoder rows over all N nodes (float4) ----------
__global__ __launch_bounds__(256) void kbcast(const float* __restrict__ rowadj,
                                              const float* __restrict__ rownodes,
                                              float* __restrict__ out){
  __shared__ float row[MAXNN+HH];
  int t=threadIdx.x;
  if(t<MAXNN) row[t]=rowadj[t];
  if(t<HH) row[MAXNN+t]=rownodes[t];
  __syncthreads();
  int stride=gridDim.x*blockDim.x;
  const int tot4 = OUT_TOT/4;          // 200 and 128 both divisible by 4
  for(int q=blockIdx.x*blockDim.x+t; q<tot4; q+=stride){
    int idx = q*4;
    float4 vv;
    if(idx<ADJ_TOT){
      int j = idx % MAXNN;             // multiple of 4 -> 16B-aligned LDS read
      vv = *(const float4*)&row[j];
    } else {
      int j = (idx-ADJ_TOT) & (HH-1);
      vv = *(const float4*)&row[MAXNN+j];
    }
    *(float4*)&out[idx] = vv;
  }
}

extern "C" void kernel_launch(void* const* d_in, const int* in_sizes, int n_in,
                              void* d_out, int out_size, void* d_ws, size_t ws_size,
                              hipStream_t stream){
  const float* x   = (const float*)d_in[0];
  const int*   ei  = (const int*)d_in[1];
  const float* ea  = (const float*)d_in[2];
  const float* eps = (const float*)d_in[3];
  const float* W1  =(const float*)d_in[5];
  const float* as1 =(const float*)d_in[6];
  const float* ad1 =(const float*)d_in[7];
  const float* We1 =(const float*)d_in[8];
  const float* ae1 =(const float*)d_in[9];
  const float* b1  =(const float*)d_in[10];
  const float* W2  =(const float*)d_in[11];
  const float* as2 =(const float*)d_in[12];
  const float* ad2 =(const float*)d_in[13];
  const float* We2 =(const float*)d_in[14];
  const float* ae2 =(const float*)d_in[15];
  const float* b2  =(const float*)d_in[16];
  const float* muW =(const float*)d_in[17];
  const float* mub =(const float*)d_in[18];
  const float* lvW =(const float*)d_in[19];
  const float* lvb =(const float*)d_in[20];
  const float* decW=(const float*)d_in[21];
  const float* decb=(const float*)d_in[22];
  const float* aW1 =(const float*)d_in[23];
  const float* ab1 =(const float*)d_in[24];
  const float* aW2 =(const float*)d_in[25];
  const float* ab2 =(const float*)d_in[26];
  const float* nW1 =(const float*)d_in[27];
  const float* nb1 =(const float*)d_in[28];
  const float* nW2 =(const float*)d_in[29];
  const float* nb2 =(const float*)d_in[30];
  float* out=(float*)d_out;

  char* w=(char*)d_ws;
  unsigned char*  A8  = (unsigned char*)w;  w += (size_t)NN*HH;      // 6.4 MB fp8
  unsigned short* Bbf = (unsigned short*)w; w += (size_t)NN*HH*2;    // 12.8 MB bf16
  unsigned short* Wp1 = (unsigned short*)w; w += (size_t)HH*HH*2;
  unsigned short* Wp2 = (unsigned short*)w; w += (size_t)HH*HH*2;
  uint2*  csr      = (uint2*)w;  w += (size_t)EF*8;                  // 6.8 MB
  float*  alphabuf = (float*)w;  w += (size_t)EF*4;
  int*    srcbuf   = (int*)w;    w += (size_t)EF*4;
  unsigned short* erank = (unsigned short*)w; w += (size_t)EE*2;
  int*    rowstart = (int*)w;    w += (size_t)(NN+1)*4;
  int*    ideg     = (int*)w;    w += (size_t)NN*4;
  float*  hgsum    = (float*)w;  w += 128*4;
  float*  asrc     = (float*)w;  w += (size_t)NN*4;
  float*  adst     = (float*)w;  w += (size_t)NN*4;
  float*  wa1      = (float*)w;  w += 16*4;
  float*  wa2      = (float*)w;  w += 16*4;
  float*  rowadj   = (float*)w;  w += 256*4;
  float*  rownodes = (float*)w;  w += 128*4;
  int*    blocksum = (int*)w;    w += 64*4;

  int gatblocks  = (NN+3)/4;     // 12500

  hipLaunchKernelGGL(kprep, dim3((NN+255)/256), dim3(256), 0, stream,
                     ideg, hgsum, We1, ae1, We2, ae2, wa1, wa2, W1, W2, Wp1, Wp2);
  // gemm L1 (x @ W1) overlapped with degree/erank atomic pass
  hipLaunchKernelGGL(kdeggemm, dim3(GEMMBLOCKS+DEGBLOCKS), dim3(256), 0, stream,
                     ei, ideg, erank,
                     (const void*)x, 1, Wp1, as1, ad1, A8, asrc, adst);
  hipLaunchKernelGGL(kscan1, dim3(NBSCAN), dim3(1024), 0, stream, ideg, rowstart, blocksum);
  hipLaunchKernelGGL(kscan3i, dim3((NN+255)/256), dim3(256), 0, stream, rowstart, blocksum);
  hipLaunchKernelGGL(kscatter, dim3((EE/2+255)/256), dim3(256), 0, stream,
                     ei, ea, wa1, wa2, rowstart, erank, csr);
  // layer 1 aggregate (mode 0: computes + stores self entries)
  hipLaunchKernelGGL(kgat,  dim3(gatblocks), dim3(256), 0, stream,
                     A8, asrc, adst, rowstart, csr, 0, b1, alphabuf, srcbuf, Bbf);
  // layer 2 (bf16 input)
  hipLaunchKernelGGL(kgemm3, dim3(GEMMBLOCKS), dim3(256), 0, stream,
                     (const void*)Bbf, 0, Wp2, as2, ad2, A8, asrc, adst);
  // layer 2 aggregate (mode 1: uniform csr read, no ets chain)
  hipLaunchKernelGGL(kgat,  dim3(gatblocks), dim3(256), 0, stream,
                     A8, asrc, adst, rowstart, csr, 1, b2, alphabuf, srcbuf, Bbf);
  // graph embedding + decoder + broadcast
  hipLaunchKernelGGL(khg,   dim3(512), dim3(256), 0, stream, Bbf, hgsum);
  hipLaunchKernelGGL(kdec,  dim3(1), dim3(256), 0, stream, hgsum, eps,
                     muW,mub,lvW,lvb,decW,decb,aW1,ab1,aW2,ab2,nW1,nb1,nW2,nb2,
                     out, rowadj, rownodes);
  hipLaunchKernelGGL(kbcast, dim3(2048), dim3(256), 0, stream, rowadj, rownodes, out);
}

// Round 9
// 403.342 us; speedup vs baseline: 1.0272x; 1.0272x over previous
//
#include <hip/hip_runtime.h>
#include <math.h>

#define NN   50000
#define EE   800000
#define EF   850000   // EE + NN self loops
#define HH   128
#define FE   16
#define LATD 64
#define MAXNN 200

#define ADJ_TOT   10000000   // NN*MAXNN
#define NODES_TOT 6400000    // NN*HH
#define OUT_TOT   16400000   // ADJ_TOT + NODES_TOT
#define MU_OFF    16400000
#define LV_OFF    16400064

#define GEMMBLOCKS 782       // (NN+63)/64
#define DEGBLOCKS  782       // ceil(EE/1024): 4 edges/thread
#define NBSCAN     49        // (NN+1023)/1024

typedef __attribute__((ext_vector_type(8))) short bf16x8;
typedef __attribute__((ext_vector_type(4))) float f32x4;
typedef __attribute__((ext_vector_type(2))) float f32x2;

__device__ __forceinline__ unsigned short f2bf(float f){
  unsigned int u = __float_as_uint(f);
  unsigned int r = (u + 0x7FFFu + ((u>>16)&1u)) >> 16;   // RNE
  return (unsigned short)r;
}
__device__ __forceinline__ float bf2f(unsigned short h){
  return __uint_as_float(((unsigned int)h)<<16);
}

// ---------------- prep: zero ideg/hgsum + wa fold + W transpose/pack ----------------
__global__ __launch_bounds__(256) void kprep(int* ideg, float* hgsum,
                       const float* We1, const float* ae1, const float* We2, const float* ae2,
                       float* wa1, float* wa2,
                       const float* W1, const float* W2,
                       unsigned short* Wp1, unsigned short* Wp2){
  int i = blockIdx.x*256 + threadIdx.x;
  if(i < NN) ideg[i]=0;
  if(i < HH) hgsum[i]=0.f;
  if(i < FE){
    float s1=0.f, s2=0.f;
    for(int j=0;j<HH;j++){ s1 += We1[i*HH+j]*ae1[j]; s2 += We2[i*HH+j]*ae2[j]; }
    wa1[i]=s1; wa2[i]=s2;
  }
  if(i < HH*HH){
    int n = i >> 7, k = i & 127;
    Wp1[i] = f2bf(W1[k*HH + n]);
    Wp2[i] = f2bf(W2[k*HH + n]);
  }
}

// ---------------- MFMA GEMM body: A8 = fp8( h @ W ), fused asrc/adst ----------------
__device__ __forceinline__ void gemm_body(int bid, int tid, const void* __restrict__ hin, int h_is_fp32,
    const unsigned short* __restrict__ Wp,
    const float* __restrict__ atts, const float* __restrict__ attd,
    unsigned char* __restrict__ A8, float* __restrict__ asrc, float* __restrict__ adst){
  int lane = tid & 63;
  int wid  = tid >> 6;
  int l = lane & 15, q = lane >> 4;
  int r0 = bid*64 + wid*16;
  if(r0 >= NN) return;
  const unsigned short* hb = (const unsigned short*)hin;
  const float*          hf = (const float*)hin;
  int row = r0 + l;

  // prefetch ALL A fragments first
  bf16x8 afr[4];
  if(h_is_fp32){
    float4 u[8];
    #pragma unroll
    for(int kb=0;kb<4;kb++){
      const float* p = hf + (size_t)row*HH + kb*32 + q*8;
      u[kb*2]   = *(const float4*)(p);
      u[kb*2+1] = *(const float4*)(p+4);
    }
    #pragma unroll
    for(int kb=0;kb<4;kb++){
      afr[kb][0]=(short)f2bf(u[kb*2].x);   afr[kb][1]=(short)f2bf(u[kb*2].y);
      afr[kb][2]=(short)f2bf(u[kb*2].z);   afr[kb][3]=(short)f2bf(u[kb*2].w);
      afr[kb][4]=(short)f2bf(u[kb*2+1].x); afr[kb][5]=(short)f2bf(u[kb*2+1].y);
      afr[kb][6]=(short)f2bf(u[kb*2+1].z); afr[kb][7]=(short)f2bf(u[kb*2+1].w);
    }
  } else {
    #pragma unroll
    for(int kb=0;kb<4;kb++)
      afr[kb] = *(const bf16x8*)(hb + (size_t)row*HH + kb*32 + q*8);
  }

  f32x4 acc[8];
  #pragma unroll
  for(int t=0;t<8;t++) acc[t]=(f32x4){0.f,0.f,0.f,0.f};

  #pragma unroll
  for(int kb=0;kb<4;kb++){
    #pragma unroll
    for(int t=0;t<8;t++){
      bf16x8 b = *(const bf16x8*)(Wp + (size_t)(t*16+l)*HH + kb*32 + q*8);
      acc[t] = __builtin_amdgcn_mfma_f32_16x16x32_bf16(afr[kb], b, acc[t], 0,0,0);
    }
  }

  float av[8], dv[8];
  #pragma unroll
  for(int t=0;t<8;t++){ av[t]=atts[t*16+l]; dv[t]=attd[t*16+l]; }
  #pragma unroll
  for(int reg=0;reg<4;reg++){
    float ps=0.f, pd=0.f;
    #pragma unroll
    for(int t=0;t<8;t++){ ps+=acc[t][reg]*av[t]; pd+=acc[t][reg]*dv[t]; }
    #pragma unroll
    for(int m=8;m>=1;m>>=1){ ps+=__shfl_xor(ps,m,16); pd+=__shfl_xor(pd,m,16); }
    if(l==0){ int R=r0+q*4+reg; asrc[R]=ps; adst[R]=pd; }
  }
  #pragma unroll
  for(int t=0;t<8;t++)
    #pragma unroll
    for(int reg=0;reg<4;reg++){
      int pk = __builtin_amdgcn_cvt_pk_fp8_f32(acc[t][reg], 0.f, 0, false);
      A8[(size_t)(r0+q*4+reg)*HH + t*16 + l] = (unsigned char)(pk & 0xFF);
    }
}

__global__ __launch_bounds__(256) void kgemm3(const void* __restrict__ hin, int h_is_fp32,
    const unsigned short* __restrict__ Wp,
    const float* __restrict__ atts, const float* __restrict__ attd,
    unsigned char* __restrict__ A8, float* __restrict__ asrc, float* __restrict__ adst){
  gemm_body(blockIdx.x, threadIdx.x, hin, h_is_fp32, Wp, atts, attd, A8, asrc, adst);
}

// gemm L1 (blocks [0,GEMMBLOCKS)) + degree/erank atomics (4 edges/thread, rest).
__global__ __launch_bounds__(256) void kdeggemm(
    const int* __restrict__ ei, int* ideg, unsigned short* __restrict__ erank,
    const void* __restrict__ hin, int h_is_fp32,
    const unsigned short* __restrict__ Wp,
    const float* __restrict__ atts, const float* __restrict__ attd,
    unsigned char* __restrict__ A8, float* __restrict__ asrc, float* __restrict__ adst){
  if(blockIdx.x < GEMMBLOCKS){
    gemm_body(blockIdx.x, threadIdx.x, hin, h_is_fp32, Wp, atts, attd, A8, asrc, adst);
  } else {
    int e0 = ((blockIdx.x - GEMMBLOCKS)*256 + threadIdx.x)*4;
    if(e0 + 3 < EE){
      int4 d4 = *(const int4*)(ei + EE + e0);
      unsigned short r0 = (unsigned short)atomicAdd(&ideg[d4.x], 1);
      unsigned short r1 = (unsigned short)atomicAdd(&ideg[d4.y], 1);
      unsigned short r2 = (unsigned short)atomicAdd(&ideg[d4.z], 1);
      unsigned short r3 = (unsigned short)atomicAdd(&ideg[d4.w], 1);
      ushort4 rr; rr.x=r0; rr.y=r1; rr.z=r2; rr.w=r3;
      *(ushort4*)(erank + e0) = rr;
    } else {
      for(int j=0;j<4;j++)
        if(e0+j < EE) erank[e0+j] = (unsigned short)atomicAdd(&ideg[ei[EE+e0+j]], 1);
    }
  }
}

// ---------------- exclusive scan of rowlen = ideg+1 ----------------
__global__ void kscan1(const int* __restrict__ ideg, int* rowstart, int* blocksum){
  __shared__ int sd[1024];
  int t=threadIdx.x; int i=blockIdx.x*1024+t;
  int v = (i<NN)? (ideg[i]+1) : 0;
  sd[t]=v; __syncthreads();
  for(int off=1; off<1024; off<<=1){
    int x = (t>=off)? sd[t-off] : 0;
    __syncthreads();
    sd[t] += x;
    __syncthreads();
  }
  if(i<NN) rowstart[i] = sd[t]-v;
  if(t==1023) blocksum[blockIdx.x]=sd[1023];
}
// scan3 with inline block-sum scan (in-place +=, writes rowstart[NN])
__global__ __launch_bounds__(256) void kscan3i(int* rowstart, const int* __restrict__ blocksum){
  __shared__ int bo[64];
  int t = threadIdx.x;
  if(t < 64){
    int v = (t < NBSCAN)? blocksum[t] : 0;
    int inc = v;
    #pragma unroll
    for(int off=1; off<64; off<<=1){
      int x = __shfl_up(inc, off);
      if(t>=off) inc += x;
    }
    bo[t] = inc - v;           // exclusive; bo[NBSCAN] = total
  }
  __syncthreads();
  int i = blockIdx.x*256 + t;
  if(i<NN) rowstart[i] += bo[i>>10];
  if(i==0) rowstart[NN] = bo[NBSCAN];
}

// ---------------- CSR scatter: 2 edges/thread, packed 8B entries, NO atomic ---------
__device__ __forceinline__ unsigned etpack(const float4* a4,
                         const float* __restrict__ wa1, const float* __restrict__ wa2){
  float4 v0=a4[0], v1=a4[1], v2=a4[2], v3=a4[3];
  float va[16]={v0.x,v0.y,v0.z,v0.w, v1.x,v1.y,v1.z,v1.w,
                v2.x,v2.y,v2.z,v2.w, v3.x,v3.y,v3.z,v3.w};
  float d1=0.f,d2=0.f;
  #pragma unroll
  for(int f=0;f<FE;f++){ d1+=va[f]*wa1[f]; d2+=va[f]*wa2[f]; }
  return (unsigned)f2bf(d1) | ((unsigned)f2bf(d2)<<16);
}
__global__ __launch_bounds__(256) void kscatter(const int* __restrict__ ei, const float* __restrict__ ea,
                         const float* __restrict__ wa1, const float* __restrict__ wa2,
                         const int* __restrict__ rowstart, const unsigned short* __restrict__ erank,
                         uint2* __restrict__ csr){
  int e0 = (blockIdx.x*256 + threadIdx.x)*2;
  if(e0>=EE) return;
  int sA=ei[e0],    sB=ei[e0+1];
  int dA=ei[EE+e0], dB=ei[EE+e0+1];
  int rA=(int)erank[e0], rB=(int)erank[e0+1];
  int pA=rowstart[dA]+rA, pB=rowstart[dB]+rB;
  const float4* a4 = (const float4*)(ea + (size_t)e0*FE);
  unsigned yA = etpack(a4,   wa1, wa2);
  unsigned yB = etpack(a4+4, wa1, wa2);
  uint2 enA; enA.x=(unsigned)sA; enA.y=yA;
  uint2 enB; enB.x=(unsigned)sB; enB.y=yB;
  csr[pA]=enA; csr[pB]=enB;
}

// ---------------- GAT softmax-aggregate: TWO nodes per wave (32-lane halves) --------
// half = lane>>5 selects node; within half: lq = hl&15 (feature chunk, 8 fp8 feats),
// qq = hl>>4 (edge sub-slot 0/1). Slot t covers edges 2t,2t+1; batch of 6 loads = 12
// edges in flight. All reductions width-32 (xor masks <=16 are half-local).
// mode 0: self-loop et means computed + self entry written to csr; mode 1: uniform.
__global__ __launch_bounds__(256) void kgat(const unsigned char* __restrict__ A8,
    const float* __restrict__ asrc, const float* __restrict__ adst,
    const int* __restrict__ rowstart, uint2* __restrict__ csr,
    int mode, const float* __restrict__ bias,
    float* __restrict__ alphabuf, int* __restrict__ srcbuf,
    unsigned short* __restrict__ Bout){
  int lane = threadIdx.x & 63;
  int wid  = threadIdx.x >> 6;
  int half = lane >> 5;               // node select within wave
  int hl   = lane & 31;               // lane within half
  int i = blockIdx.x*8 + wid*2 + half;
  if(i >= NN) return;
  int base = rowstart[i];
  int len  = rowstart[i+1]-base;      // deg + 1 (self)
  float adi = adst[i];
  int lq = hl & 15;                   // feature chunk (feats lq*8 .. lq*8+7)
  int qq = hl >> 4;                   // edge sub-slot 0..1
  float av[8];
  #pragma unroll
  for(int j=0;j<8;j++) av[j]=0.f;

  if(__builtin_expect(len <= 32, 1)){
    int P2 = (len+1)>>1;               // 1..16 pair slots
    // ---- load csr entry; finalize s for all lanes of this half ----
    int nread = mode ? len : len-1;
    int s = i; float etlo = 0.f, ethi = 0.f;
    if(hl < nread){
      uint2 en = csr[base+hl];
      s = (int)en.x;
      etlo = bf2f((unsigned short)(en.y & 0xFFFFu));
      ethi = bf2f((unsigned short)(en.y >> 16));
    }
    float et = mode ? ethi : etlo;
    // ---- prefetch gather batch 0 (addresses need only s) ----
    int skv0[6];
    #pragma unroll
    for(int j=0;j<6;j++) skv0[j] = (j<P2) ? __shfl(s, 2*j+qq, 32) : i;
    unsigned ux[6], uy[6];
    #pragma unroll
    for(int j=0;j<6;j++){
      uint2 u = *(const uint2*)(A8 + (size_t)skv0[j]*HH + lq*8);
      ux[j]=u.x; uy[j]=u.y;
    }
    // ---- mode 0: self-loop et means (both halves of packed et), write self entry ----
    if(!mode){
      float e1 = (hl < len-1) ? etlo : 0.f;
      float e2 = (hl < len-1) ? ethi : 0.f;
      #pragma unroll
      for(int mk=16;mk>=1;mk>>=1){ e1 += __shfl_xor(e1,mk); e2 += __shfl_xor(e2,mk); }
      float dg = fmaxf((float)(len-1), 1.f);
      float m1 = e1/dg, m2 = e2/dg;
      if(hl == len-1){
        et = m1;
        uint2 se; se.x=(unsigned)i;
        se.y=(unsigned)f2bf(m1) | ((unsigned)f2bf(m2)<<16);
        csr[base+len-1] = se;
      }
    }
    // ---- softmax (width-32) ----
    float a = -1e30f;
    if(hl < len){
      a = asrc[s] + adi + et;
      a = fmaxf(a, 0.2f*a);            // leaky_relu 0.2
    }
    float m = a;
    #pragma unroll
    for(int mk=16;mk>=1;mk>>=1) m = fmaxf(m, __shfl_xor(m,mk));
    float ex = (hl<len) ? __expf(a-m) : 0.f;
    float sm = ex;
    #pragma unroll
    for(int mk=16;mk>=1;mk>>=1) sm += __shfl_xor(sm,mk);
    ex *= __builtin_amdgcn_rcpf(sm);   // fold 1/den into the weight

    // ---- consume batch 0 ----
    float w0[6];
    #pragma unroll
    for(int j=0;j<6;j++) w0[j] = (j<P2) ? __shfl(ex, 2*j+qq, 32) : 0.f;
    #pragma unroll
    for(int j=0;j<6;j++){
      f32x2 v;
      v=__builtin_amdgcn_cvt_pk_f32_fp8((int)ux[j],false); av[0]+=w0[j]*v[0]; av[1]+=w0[j]*v[1];
      v=__builtin_amdgcn_cvt_pk_f32_fp8((int)ux[j],true ); av[2]+=w0[j]*v[0]; av[3]+=w0[j]*v[1];
      v=__builtin_amdgcn_cvt_pk_f32_fp8((int)uy[j],false); av[4]+=w0[j]*v[0]; av[5]+=w0[j]*v[1];
      v=__builtin_amdgcn_cvt_pk_f32_fp8((int)uy[j],true ); av[6]+=w0[j]*v[0]; av[7]+=w0[j]*v[1];
    }
    // ---- remaining batches (len > 12 only) ----
    for(int t0=6; t0<P2; t0+=6){
      int skv[6]; float w[6];
      #pragma unroll
      for(int j=0;j<6;j++){
        if(t0+j < P2){
          int idx = 2*(t0+j) + qq;     // <= 31
          skv[j] = __shfl(s, idx, 32);
          w[j]   = __shfl(ex, idx, 32);
        } else { skv[j] = i; w[j] = 0.f; }
      }
      unsigned vx[6], vy[6];
      #pragma unroll
      for(int j=0;j<6;j++){
        uint2 u = *(const uint2*)(A8 + (size_t)skv[j]*HH + lq*8);
        vx[j]=u.x; vy[j]=u.y;
      }
      #pragma unroll
      for(int j=0;j<6;j++){
        f32x2 v;
        v=__builtin_amdgcn_cvt_pk_f32_fp8((int)vx[j],false); av[0]+=w[j]*v[0]; av[1]+=w[j]*v[1];
        v=__builtin_amdgcn_cvt_pk_f32_fp8((int)vx[j],true ); av[2]+=w[j]*v[0]; av[3]+=w[j]*v[1];
        v=__builtin_amdgcn_cvt_pk_f32_fp8((int)vy[j],false); av[4]+=w[j]*v[0]; av[5]+=w[j]*v[1];
        v=__builtin_amdgcn_cvt_pk_f32_fp8((int)vy[j],true ); av[6]+=w[j]*v[0]; av[7]+=w[j]*v[1];
      }
    }
  } else {
    // rare fallback (len > 32): strided two-pass with global spill, width-32
    int deg = len-1;
    int lim = mode ? len : deg;
    float lm = -1e30f, e1 = 0.f, e2 = 0.f;
    for(int k=hl;k<lim;k+=32){
      uint2 en = csr[base+k];
      int sr = (int)en.x;
      float lo = bf2f((unsigned short)(en.y & 0xFFFFu));
      float hi = bf2f((unsigned short)(en.y >> 16));
      float etv = mode ? hi : lo;
      if(!mode){ e1 += lo; e2 += hi; }
      float a = asrc[sr] + adi + etv;
      a = fmaxf(a, 0.2f*a);
      alphabuf[base+k]=a; srcbuf[base+k]=sr;
      lm = fmaxf(lm,a);
    }
    #pragma unroll
    for(int mk=16;mk>=1;mk>>=1){
      e1 += __shfl_xor(e1,mk);
      e2 += __shfl_xor(e2,mk);
      lm  = fmaxf(lm, __shfl_xor(lm,mk));
    }
    float aself = 0.f;
    if(!mode){
      float m1 = e1/(float)deg, m2 = e2/(float)deg;
      aself = asrc[i] + adi + m1;
      aself = fmaxf(aself, 0.2f*aself);
      lm = fmaxf(lm, aself);
      if(hl==0){
        uint2 se; se.x=(unsigned)i;
        se.y=(unsigned)f2bf(m1) | ((unsigned)f2bf(m2)<<16);
        csr[base+deg] = se;
      }
    }
    float ls=0.f;
    for(int k=hl;k<len;k+=32){
      float a;
      if(mode) a = alphabuf[base+k];
      else     a = (k<deg)? alphabuf[base+k] : aself;
      float e_ = __expf(a-lm);
      alphabuf[base+k]=e_;
      ls += e_;
    }
    #pragma unroll
    for(int mk=16;mk>=1;mk>>=1) ls += __shfl_xor(ls,mk);
    float inv = 1.f/ls;
    int lim2 = mode ? len : deg;
    int P2 = (len+1)>>1;
    for(int t=0;t<P2;t++){
      int k = 2*t + qq;
      int sk = i; float wk = 0.f;
      if(k<len){
        sk = (k<lim2)? srcbuf[base+k] : i;
        wk = alphabuf[base+k]*inv;
      }
      uint2 u = *(const uint2*)(A8 + (size_t)sk*HH + lq*8);
      f32x2 v;
      v=__builtin_amdgcn_cvt_pk_f32_fp8((int)u.x,false); av[0]+=wk*v[0]; av[1]+=wk*v[1];
      v=__builtin_amdgcn_cvt_pk_f32_fp8((int)u.x,true ); av[2]+=wk*v[0]; av[3]+=wk*v[1];
      v=__builtin_amdgcn_cvt_pk_f32_fp8((int)u.y,false); av[4]+=wk*v[0]; av[5]+=wk*v[1];
      v=__builtin_amdgcn_cvt_pk_f32_fp8((int)u.y,true ); av[6]+=wk*v[0]; av[7]+=wk*v[1];
    }
  }

  // ---- fold the 2 edge sub-slots (xor 16 is half-local) ----
  #pragma unroll
  for(int j=0;j<8;j++) av[j] += __shfl_xor(av[j],16);
  // ---- epilogue: 16 lanes per half store uint4 = full 256B bf16 row ----
  if(qq==0){
    const float4* bp = (const float4*)(bias + lq*8);
    float4 b0=bp[0], b1=bp[1];
    float o0=fmaxf(av[0]+b0.x,0.f), o1=fmaxf(av[1]+b0.y,0.f);
    float o2=fmaxf(av[2]+b0.z,0.f), o3=fmaxf(av[3]+b0.w,0.f);
    float o4=fmaxf(av[4]+b1.x,0.f), o5=fmaxf(av[5]+b1.y,0.f);
    float o6=fmaxf(av[6]+b1.z,0.f), o7=fmaxf(av[7]+b1.w,0.f);
    uint4 ov;
    ov.x=(unsigned)f2bf(o0)|((unsigned)f2bf(o1)<<16);
    ov.y=(unsigned)f2bf(o2)|((unsigned)f2bf(o3)<<16);
    ov.z=(unsigned)f2bf(o4)|((unsigned)f2bf(o5)<<16);
    ov.w=(unsigned)f2bf(o6)|((unsigned)f2bf(o7)<<16);
    *(uint4*)(Bout + (size_t)i*HH + lq*8) = ov;
  }
}

// ---------------- column mean (bf16 input): grid-strided, 512 blocks ----------------
__global__ __launch_bounds__(256) void khg(const unsigned short* __restrict__ B, float* hgsum){
  int f = threadIdx.x & 127;      // column
  int half = threadIdx.x >> 7;    // 0/1
  float s=0.f;
  for(int i = blockIdx.x*2+half; i < NN; i += gridDim.x*2)
    s += bf2f(B[(size_t)i*HH + f]);
  __shared__ float sd[256];
  sd[threadIdx.x]=s; __syncthreads();
  if(half==0) atomicAdd(&hgsum[f], sd[threadIdx.x]+sd[threadIdx.x+128]);
}

// ---------------- tiny decoder, single block ----------------
__global__ __launch_bounds__(256) void kdec(const float* __restrict__ hgsum, const float* __restrict__ eps,
   const float* muW,const float* mub,const float* lvW,const float* lvb,
   const float* decW,const float* decb,
   const float* aW1,const float* ab1,const float* aW2,const float* ab2,
   const float* nW1,const float* nb1,const float* nW2,const float* nb2,
   float* out, float* rowadj, float* rownodes){
  __shared__ float hg[HH], z[LATD], hd[HH], t1[HH], t2[HH];
  int t=threadIdx.x;
  if(t<HH) hg[t]=hgsum[t]*(1.0f/NN);
  __syncthreads();
  if(t<LATD){
    float mu=mub[t], lv=lvb[t];
    #pragma unroll 8
    for(int k=0;k<HH;k++){ mu += hg[k]*muW[k*LATD+t]; lv += hg[k]*lvW[k*LATD+t]; }
    out[MU_OFF+t]=mu; out[LV_OFF+t]=lv;
    z[t]=mu + eps[t]*expf(0.5f*lv);
  }
  __syncthreads();
  if(t<HH){
    float a=decb[t];
    #pragma unroll 8
    for(int k=0;k<LATD;k++) a += z[k]*decW[k*HH+t];
    hd[t]=fmaxf(a,0.f);
  }
  __syncthreads();
  if(t<HH){
    float a=ab1[t];
    #pragma unroll 8
    for(int k=0;k<HH;k++) a += hd[k]*aW1[k*HH+t];
    t1[t]=fmaxf(a,0.f);
  } else {
    int j=t-HH;
    float a=nb1[j];
    #pragma unroll 8
    for(int k=0;k<HH;k++) a += hd[k]*nW1[k*HH+j];
    t2[j]=fmaxf(a,0.f);
  }
  __syncthreads();
  for(int j=t;j<MAXNN;j+=256){
    float a=ab2[j];
    #pragma unroll 8
    for(int k=0;k<HH;k++) a += t1[k]*aW2[k*MAXNN+j];
    rowadj[j]=a;
  }
  if(t<HH){
    float a=nb2[t];
    #pragma unroll 8
    for(int k=0;k<HH;k++) a += t2[k]*nW2[k*HH+t];
    rownodes[t]=a;
  }
}

// ---------------- broadcast the two decoder rows over all N nodes (float4) ----------
__global__ __launch_bounds__(256) void kbcast(const float* __restrict__ rowadj,
                                              const float* __restrict__ rownodes,
                                              float* __restrict__ out){
  __shared__ float row[MAXNN+HH];
  int t=threadIdx.x;
  if(t<MAXNN) row[t]=rowadj[t];
  if(t<HH) row[MAXNN+t]=rownodes[t];
  __syncthreads();
  int stride=gridDim.x*blockDim.x;
  const int tot4 = OUT_TOT/4;          // 200 and 128 both divisible by 4
  for(int q=blockIdx.x*blockDim.x+t; q<tot4; q+=stride){
    int idx = q*4;
    float4 vv;
    if(idx<ADJ_TOT){
      int j = idx % MAXNN;             // multiple of 4 -> 16B-aligned LDS read
      vv = *(const float4*)&row[j];
    } else {
      int j = (idx-ADJ_TOT) & (HH-1);
      vv = *(const float4*)&row[MAXNN+j];
    }
    *(float4*)&out[idx] = vv;
  }
}

extern "C" void kernel_launch(void* const* d_in, const int* in_sizes, int n_in,
                              void* d_out, int out_size, void* d_ws, size_t ws_size,
                              hipStream_t stream){
  const float* x   = (const float*)d_in[0];
  const int*   ei  = (const int*)d_in[1];
  const float* ea  = (const float*)d_in[2];
  const float* eps = (const float*)d_in[3];
  const float* W1  =(const float*)d_in[5];
  const float* as1 =(const float*)d_in[6];
  const float* ad1 =(const float*)d_in[7];
  const float* We1 =(const float*)d_in[8];
  const float* ae1 =(const float*)d_in[9];
  const float* b1  =(const float*)d_in[10];
  const float* W2  =(const float*)d_in[11];
  const float* as2 =(const float*)d_in[12];
  const float* ad2 =(const float*)d_in[13];
  const float* We2 =(const float*)d_in[14];
  const float* ae2 =(const float*)d_in[15];
  const float* b2  =(const float*)d_in[16];
  const float* muW =(const float*)d_in[17];
  const float* mub =(const float*)d_in[18];
  const float* lvW =(const float*)d_in[19];
  const float* lvb =(const float*)d_in[20];
  const float* decW=(const float*)d_in[21];
  const float* decb=(const float*)d_in[22];
  const float* aW1 =(const float*)d_in[23];
  const float* ab1 =(const float*)d_in[24];
  const float* aW2 =(const float*)d_in[25];
  const float* ab2 =(const float*)d_in[26];
  const float* nW1 =(const float*)d_in[27];
  const float* nb1 =(const float*)d_in[28];
  const float* nW2 =(const float*)d_in[29];
  const float* nb2 =(const float*)d_in[30];
  float* out=(float*)d_out;

  char* w=(char*)d_ws;
  unsigned char*  A8  = (unsigned char*)w;  w += (size_t)NN*HH;      // 6.4 MB fp8
  unsigned short* Bbf = (unsigned short*)w; w += (size_t)NN*HH*2;    // 12.8 MB bf16
  unsigned short* Wp1 = (unsigned short*)w; w += (size_t)HH*HH*2;
  unsigned short* Wp2 = (unsigned short*)w; w += (size_t)HH*HH*2;
  uint2*  csr      = (uint2*)w;  w += (size_t)EF*8;                  // 6.8 MB
  float*  alphabuf = (float*)w;  w += (size_t)EF*4;
  int*    srcbuf   = (int*)w;    w += (size_t)EF*4;
  unsigned short* erank = (unsigned short*)w; w += (size_t)EE*2;
  int*    rowstart = (int*)w;    w += (size_t)(NN+1)*4;
  int*    ideg     = (int*)w;    w += (size_t)NN*4;
  float*  hgsum    = (float*)w;  w += 128*4;
  float*  asrc     = (float*)w;  w += (size_t)NN*4;
  float*  adst     = (float*)w;  w += (size_t)NN*4;
  float*  wa1      = (float*)w;  w += 16*4;
  float*  wa2      = (float*)w;  w += 16*4;
  float*  rowadj   = (float*)w;  w += 256*4;
  float*  rownodes = (float*)w;  w += 128*4;
  int*    blocksum = (int*)w;    w += 64*4;

  int gatblocks  = (NN+7)/8;     // 6250 (2 nodes per wave, 8 per block)

  hipLaunchKernelGGL(kprep, dim3((NN+255)/256), dim3(256), 0, stream,
                     ideg, hgsum, We1, ae1, We2, ae2, wa1, wa2, W1, W2, Wp1, Wp2);
  // gemm L1 (x @ W1) overlapped with degree/erank atomic pass
  hipLaunchKernelGGL(kdeggemm, dim3(GEMMBLOCKS+DEGBLOCKS), dim3(256), 0, stream,
                     ei, ideg, erank,
                     (const void*)x, 1, Wp1, as1, ad1, A8, asrc, adst);
  hipLaunchKernelGGL(kscan1, dim3(NBSCAN), dim3(1024), 0, stream, ideg, rowstart, blocksum);
  hipLaunchKernelGGL(kscan3i, dim3((NN+255)/256), dim3(256), 0, stream, rowstart, blocksum);
  hipLaunchKernelGGL(kscatter, dim3((EE/2+255)/256), dim3(256), 0, stream,
                     ei, ea, wa1, wa2, rowstart, erank, csr);
  // layer 1 aggregate (mode 0: computes + stores self entries)
  hipLaunchKernelGGL(kgat,  dim3(gatblocks), dim3(256), 0, stream,
                     A8, asrc, adst, rowstart, csr, 0, b1, alphabuf, srcbuf, Bbf);
  // layer 2 (bf16 input)
  hipLaunchKernelGGL(kgemm3, dim3(GEMMBLOCKS), dim3(256), 0, stream,
                     (const void*)Bbf, 0, Wp2, as2, ad2, A8, asrc, adst);
  // layer 2 aggregate (mode 1: uniform csr read, no ets chain)
  hipLaunchKernelGGL(kgat,  dim3(gatblocks), dim3(256), 0, stream,
                     A8, asrc, adst, rowstart, csr, 1, b2, alphabuf, srcbuf, Bbf);
  // graph embedding + decoder + broadcast
  hipLaunchKernelGGL(khg,   dim3(512), dim3(256), 0, stream, Bbf, hgsum);
  hipLaunchKernelGGL(kdec,  dim3(1), dim3(256), 0, stream, hgsum, eps,
                     muW,mub,lvW,lvb,decW,decb,aW1,ab1,aW2,ab2,nW1,nb1,nW2,nb2,
                     out, rowadj, rownodes);
  hipLaunchKernelGGL(kbcast, dim3(2048), dim3(256), 0, stream, rowadj, rownodes, out);
}

// Round 10
// 399.047 us; speedup vs baseline: 1.0382x; 1.0108x over previous
//
#include <hip/hip_runtime.h>
#include <math.h>

#define NN   50000
#define EE   800000
#define EF   850000   // EE + NN self loops
#define HH   128
#define FE   16
#define LATD 64
#define MAXNN 200

#define ADJ_TOT   10000000   // NN*MAXNN
#define NODES_TOT 6400000    // NN*HH
#define OUT_TOT   16400000   // ADJ_TOT + NODES_TOT
#define MU_OFF    16400000
#define LV_OFF    16400064

#define GEMMBLOCKS 782       // (NN+63)/64
#define DEGBLOCKS  782       // ceil(EE/1024): 4 edges/thread
#define NBSCAN     49        // (NN+1023)/1024
#define FLAGBIT    0x80000000u

typedef __attribute__((ext_vector_type(8))) short bf16x8;
typedef __attribute__((ext_vector_type(4))) float f32x4;
typedef __attribute__((ext_vector_type(2))) float f32x2;

__device__ __forceinline__ unsigned short f2bf(float f){
  unsigned int u = __float_as_uint(f);
  unsigned int r = (u + 0x7FFFu + ((u>>16)&1u)) >> 16;   // RNE
  return (unsigned short)r;
}
__device__ __forceinline__ float bf2f(unsigned short h){
  return __uint_as_float(((unsigned int)h)<<16);
}

// ---------------- prep: zero ideg/hgsum/scanpub + wa fold + W transpose/pack --------
__global__ __launch_bounds__(256) void kprep(int* ideg, float* hgsum, unsigned* scanpub,
                       const float* We1, const float* ae1, const float* We2, const float* ae2,
                       float* wa1, float* wa2,
                       const float* W1, const float* W2,
                       unsigned short* Wp1, unsigned short* Wp2){
  int i = blockIdx.x*256 + threadIdx.x;
  if(i < NN) ideg[i]=0;
  if(i < HH) hgsum[i]=0.f;
  if(i < 64) scanpub[i]=0u;
  if(i < FE){
    float s1=0.f, s2=0.f;
    for(int j=0;j<HH;j++){ s1 += We1[i*HH+j]*ae1[j]; s2 += We2[i*HH+j]*ae2[j]; }
    wa1[i]=s1; wa2[i]=s2;
  }
  if(i < HH*HH){
    int n = i >> 7, k = i & 127;
    Wp1[i] = f2bf(W1[k*HH + n]);
    Wp2[i] = f2bf(W2[k*HH + n]);
  }
}

// ---------------- MFMA GEMM body: A8 = fp8( h @ W ), fused asrc/adst ----------------
__device__ __forceinline__ void gemm_body(int bid, int tid, const void* __restrict__ hin, int h_is_fp32,
    const unsigned short* __restrict__ Wp,
    const float* __restrict__ atts, const float* __restrict__ attd,
    unsigned char* __restrict__ A8, float* __restrict__ asrc, float* __restrict__ adst){
  int lane = tid & 63;
  int wid  = tid >> 6;
  int l = lane & 15, q = lane >> 4;
  int r0 = bid*64 + wid*16;
  if(r0 >= NN) return;
  const unsigned short* hb = (const unsigned short*)hin;
  const float*          hf = (const float*)hin;
  int row = r0 + l;

  // prefetch ALL A fragments first
  bf16x8 afr[4];
  if(h_is_fp32){
    float4 u[8];
    #pragma unroll
    for(int kb=0;kb<4;kb++){
      const float* p = hf + (size_t)row*HH + kb*32 + q*8;
      u[kb*2]   = *(const float4*)(p);
      u[kb*2+1] = *(const float4*)(p+4);
    }
    #pragma unroll
    for(int kb=0;kb<4;kb++){
      afr[kb][0]=(short)f2bf(u[kb*2].x);   afr[kb][1]=(short)f2bf(u[kb*2].y);
      afr[kb][2]=(short)f2bf(u[kb*2].z);   afr[kb][3]=(short)f2bf(u[kb*2].w);
      afr[kb][4]=(short)f2bf(u[kb*2+1].x); afr[kb][5]=(short)f2bf(u[kb*2+1].y);
      afr[kb][6]=(short)f2bf(u[kb*2+1].z); afr[kb][7]=(short)f2bf(u[kb*2+1].w);
    }
  } else {
    #pragma unroll
    for(int kb=0;kb<4;kb++)
      afr[kb] = *(const bf16x8*)(hb + (size_t)row*HH + kb*32 + q*8);
  }

  f32x4 acc[8];
  #pragma unroll
  for(int t=0;t<8;t++) acc[t]=(f32x4){0.f,0.f,0.f,0.f};

  #pragma unroll
  for(int kb=0;kb<4;kb++){
    #pragma unroll
    for(int t=0;t<8;t++){
      bf16x8 b = *(const bf16x8*)(Wp + (size_t)(t*16+l)*HH + kb*32 + q*8);
      acc[t] = __builtin_amdgcn_mfma_f32_16x16x32_bf16(afr[kb], b, acc[t], 0,0,0);
    }
  }

  float av[8], dv[8];
  #pragma unroll
  for(int t=0;t<8;t++){ av[t]=atts[t*16+l]; dv[t]=attd[t*16+l]; }
  #pragma unroll
  for(int reg=0;reg<4;reg++){
    float ps=0.f, pd=0.f;
    #pragma unroll
    for(int t=0;t<8;t++){ ps+=acc[t][reg]*av[t]; pd+=acc[t][reg]*dv[t]; }
    #pragma unroll
    for(int m=8;m>=1;m>>=1){ ps+=__shfl_xor(ps,m,16); pd+=__shfl_xor(pd,m,16); }
    if(l==0){ int R=r0+q*4+reg; asrc[R]=ps; adst[R]=pd; }
  }
  #pragma unroll
  for(int t=0;t<8;t++)
    #pragma unroll
    for(int reg=0;reg<4;reg++){
      int pk = __builtin_amdgcn_cvt_pk_fp8_f32(acc[t][reg], 0.f, 0, false);
      A8[(size_t)(r0+q*4+reg)*HH + t*16 + l] = (unsigned char)(pk & 0xFF);
    }
}

__global__ __launch_bounds__(256) void kgemm3(const void* __restrict__ hin, int h_is_fp32,
    const unsigned short* __restrict__ Wp,
    const float* __restrict__ atts, const float* __restrict__ attd,
    unsigned char* __restrict__ A8, float* __restrict__ asrc, float* __restrict__ adst){
  gemm_body(blockIdx.x, threadIdx.x, hin, h_is_fp32, Wp, atts, attd, A8, asrc, adst);
}

__device__ __forceinline__ unsigned etpack(const float4* a4,
                         const float* __restrict__ wa1, const float* __restrict__ wa2){
  float4 v0=a4[0], v1=a4[1], v2=a4[2], v3=a4[3];
  float va[16]={v0.x,v0.y,v0.z,v0.w, v1.x,v1.y,v1.z,v1.w,
                v2.x,v2.y,v2.z,v2.w, v3.x,v3.y,v3.z,v3.w};
  float d1=0.f,d2=0.f;
  #pragma unroll
  for(int f=0;f<FE;f++){ d1+=va[f]*wa1[f]; d2+=va[f]*wa2[f]; }
  return (unsigned)f2bf(d1) | ((unsigned)f2bf(d2)<<16);
}

// gemm L1 (blocks [0,GEMMBLOCKS)) + deg atomics WITH intra-thread etpack overlap:
// each deg thread issues its 4 returning atomics, then streams+packs its 4 edges'
// attrs while the atomics are in flight (erank store is the only return consumer).
__global__ __launch_bounds__(256) void kdeggemm(
    const int* __restrict__ ei, int* ideg, unsigned short* __restrict__ erank,
    const float* __restrict__ ea, const float* __restrict__ wa1, const float* __restrict__ wa2,
    unsigned* __restrict__ ety,
    const void* __restrict__ hin, int h_is_fp32,
    const unsigned short* __restrict__ Wp,
    const float* __restrict__ atts, const float* __restrict__ attd,
    unsigned char* __restrict__ A8, float* __restrict__ asrc, float* __restrict__ adst){
  if(blockIdx.x < GEMMBLOCKS){
    gemm_body(blockIdx.x, threadIdx.x, hin, h_is_fp32, Wp, atts, attd, A8, asrc, adst);
  } else {
    int e0 = ((blockIdx.x - GEMMBLOCKS)*256 + threadIdx.x)*4;
    if(e0 + 3 < EE){
      int4 d4 = *(const int4*)(ei + EE + e0);
      // 4 returning atomics issued first...
      unsigned short r0 = (unsigned short)atomicAdd(&ideg[d4.x], 1);
      unsigned short r1 = (unsigned short)atomicAdd(&ideg[d4.y], 1);
      unsigned short r2 = (unsigned short)atomicAdd(&ideg[d4.z], 1);
      unsigned short r3 = (unsigned short)atomicAdd(&ideg[d4.w], 1);
      // ...edge-attr dot products stream while they're in flight
      const float4* a4 = (const float4*)(ea + (size_t)e0*FE);
      uint4 y;
      y.x = etpack(a4,    wa1, wa2);
      y.y = etpack(a4+4,  wa1, wa2);
      y.z = etpack(a4+8,  wa1, wa2);
      y.w = etpack(a4+12, wa1, wa2);
      *(uint4*)(ety + e0) = y;
      ushort4 rr; rr.x=r0; rr.y=r1; rr.z=r2; rr.w=r3;
      *(ushort4*)(erank + e0) = rr;
    }
  }
}

// ---------------- single-pass scan of rowlen = ideg+1 (publish + all-spin) ----------
// 49 blocks; each publishes its flagged aggregate (device-scope atomic), all blocks
// spin-read the 49 aggregates (all co-resident on 256 CUs), wave-scan locally.
__global__ void kscanf(const int* __restrict__ ideg, int* __restrict__ rowstart,
                       unsigned* __restrict__ scanpub){
  __shared__ int sd[1024];
  __shared__ int bo[64];
  int t=threadIdx.x, b=blockIdx.x;
  int i = b*1024 + t;
  int v = (i<NN)? (ideg[i]+1) : 0;
  sd[t]=v; __syncthreads();
  for(int off=1; off<1024; off<<=1){
    int x=(t>=off)? sd[t-off]:0; __syncthreads();
    sd[t]+=x; __syncthreads();
  }
  if(t==1023) atomicExch(&scanpub[b], (unsigned)sd[1023] | FLAGBIT);
  if(t<64){
    int j = (t<NBSCAN)? t : NBSCAN-1;
    unsigned u;
    do { u = atomicAdd(&scanpub[j], 0u); } while(!(u & FLAGBIT));
    int agg = (t<NBSCAN)? (int)(u & ~FLAGBIT) : 0;
    int inc = agg;
    #pragma unroll
    for(int off=1; off<64; off<<=1){
      int x = __shfl_up(inc, off);
      if(t>=off) inc += x;
    }
    bo[t] = inc - agg;         // exclusive; bo[NBSCAN] = total
  }
  __syncthreads();
  if(i<NN) rowstart[i] = sd[t]-v + bo[b];
  if(b==0 && t==0) rowstart[NN] = bo[NBSCAN];
}

// ---------------- CSR scatter: light reshuffle, 4 edges/thread ---------------------
__global__ __launch_bounds__(256) void kscatter(const int* __restrict__ ei,
                         const unsigned* __restrict__ ety,
                         const int* __restrict__ rowstart,
                         const unsigned short* __restrict__ erank,
                         uint2* __restrict__ csr){
  int e0 = (blockIdx.x*256 + threadIdx.x)*4;
  if(e0 >= EE) return;
  int4 s4 = *(const int4*)(ei + e0);
  int4 d4 = *(const int4*)(ei + EE + e0);
  ushort4 r4 = *(const ushort4*)(erank + e0);
  uint4 y4 = *(const uint4*)(ety + e0);
  uint2 en;
  en.x=(unsigned)s4.x; en.y=y4.x; csr[rowstart[d4.x]+(int)r4.x]=en;
  en.x=(unsigned)s4.y; en.y=y4.y; csr[rowstart[d4.y]+(int)r4.y]=en;
  en.x=(unsigned)s4.z; en.y=y4.z; csr[rowstart[d4.z]+(int)r4.z]=en;
  en.x=(unsigned)s4.w; en.y=y4.w; csr[rowstart[d4.w]+(int)r4.w]=en;
}

// ---------------- GAT softmax-aggregate: TWO nodes per wave (32-lane halves) --------
__global__ __launch_bounds__(256) void kgat(const unsigned char* __restrict__ A8,
    const float* __restrict__ asrc, const float* __restrict__ adst,
    const int* __restrict__ rowstart, uint2* __restrict__ csr,
    int mode, const float* __restrict__ bias,
    float* __restrict__ alphabuf, int* __restrict__ srcbuf,
    unsigned short* __restrict__ Bout){
  int lane = threadIdx.x & 63;
  int wid  = threadIdx.x >> 6;
  int half = lane >> 5;               // node select within wave
  int hl   = lane & 31;               // lane within half
  int i = blockIdx.x*8 + wid*2 + half;
  if(i >= NN) return;
  int base = rowstart[i];
  int len  = rowstart[i+1]-base;      // deg + 1 (self)
  float adi = adst[i];
  int lq = hl & 15;                   // feature chunk (feats lq*8 .. lq*8+7)
  int qq = hl >> 4;                   // edge sub-slot 0..1
  float av[8];
  #pragma unroll
  for(int j=0;j<8;j++) av[j]=0.f;

  if(__builtin_expect(len <= 32, 1)){
    int P2 = (len+1)>>1;               // 1..16 pair slots
    int nread = mode ? len : len-1;
    int s = i; float etlo = 0.f, ethi = 0.f;
    if(hl < nread){
      uint2 en = csr[base+hl];
      s = (int)en.x;
      etlo = bf2f((unsigned short)(en.y & 0xFFFFu));
      ethi = bf2f((unsigned short)(en.y >> 16));
    }
    float et = mode ? ethi : etlo;
    // ---- prefetch gather batch 0 (addresses need only s) ----
    int skv0[6];
    #pragma unroll
    for(int j=0;j<6;j++) skv0[j] = (j<P2) ? __shfl(s, 2*j+qq, 32) : i;
    unsigned ux[6], uy[6];
    #pragma unroll
    for(int j=0;j<6;j++){
      uint2 u = *(const uint2*)(A8 + (size_t)skv0[j]*HH + lq*8);
      ux[j]=u.x; uy[j]=u.y;
    }
    // ---- mode 0: self-loop et means, write self entry ----
    if(!mode){
      float e1 = (hl < len-1) ? etlo : 0.f;
      float e2 = (hl < len-1) ? ethi : 0.f;
      #pragma unroll
      for(int mk=16;mk>=1;mk>>=1){ e1 += __shfl_xor(e1,mk); e2 += __shfl_xor(e2,mk); }
      float dg = fmaxf((float)(len-1), 1.f);
      float m1 = e1/dg, m2 = e2/dg;
      if(hl == len-1){
        et = m1;
        uint2 se; se.x=(unsigned)i;
        se.y=(unsigned)f2bf(m1) | ((unsigned)f2bf(m2)<<16);
        csr[base+len-1] = se;
      }
    }
    // ---- softmax (width-32) ----
    float a = -1e30f;
    if(hl < len){
      a = asrc[s] + adi + et;
      a = fmaxf(a, 0.2f*a);            // leaky_relu 0.2
    }
    float m = a;
    #pragma unroll
    for(int mk=16;mk>=1;mk>>=1) m = fmaxf(m, __shfl_xor(m,mk));
    float ex = (hl<len) ? __expf(a-m) : 0.f;
    float sm = ex;
    #pragma unroll
    for(int mk=16;mk>=1;mk>>=1) sm += __shfl_xor(sm,mk);
    ex *= __builtin_amdgcn_rcpf(sm);   // fold 1/den into the weight

    // ---- consume batch 0 ----
    float w0[6];
    #pragma unroll
    for(int j=0;j<6;j++) w0[j] = (j<P2) ? __shfl(ex, 2*j+qq, 32) : 0.f;
    #pragma unroll
    for(int j=0;j<6;j++){
      f32x2 v;
      v=__builtin_amdgcn_cvt_pk_f32_fp8((int)ux[j],false); av[0]+=w0[j]*v[0]; av[1]+=w0[j]*v[1];
      v=__builtin_amdgcn_cvt_pk_f32_fp8((int)ux[j],true ); av[2]+=w0[j]*v[0]; av[3]+=w0[j]*v[1];
      v=__builtin_amdgcn_cvt_pk_f32_fp8((int)uy[j],false); av[4]+=w0[j]*v[0]; av[5]+=w0[j]*v[1];
      v=__builtin_amdgcn_cvt_pk_f32_fp8((int)uy[j],true ); av[6]+=w0[j]*v[0]; av[7]+=w0[j]*v[1];
    }
    // ---- remaining batches (len > 12 only) ----
    for(int t0=6; t0<P2; t0+=6){
      int skv[6]; float w[6];
      #pragma unroll
      for(int j=0;j<6;j++){
        if(t0+j < P2){
          int idx = 2*(t0+j) + qq;     // <= 31
          skv[j] = __shfl(s, idx, 32);
          w[j]   = __shfl(ex, idx, 32);
        } else { skv[j] = i; w[j] = 0.f; }
      }
      unsigned vx[6], vy[6];
      #pragma unroll
      for(int j=0;j<6;j++){
        uint2 u = *(const uint2*)(A8 + (size_t)skv[j]*HH + lq*8);
        vx[j]=u.x; vy[j]=u.y;
      }
      #pragma unroll
      for(int j=0;j<6;j++){
        f32x2 v;
        v=__builtin_amdgcn_cvt_pk_f32_fp8((int)vx[j],false); av[0]+=w[j]*v[0]; av[1]+=w[j]*v[1];
        v=__builtin_amdgcn_cvt_pk_f32_fp8((int)vx[j],true ); av[2]+=w[j]*v[0]; av[3]+=w[j]*v[1];
        v=__builtin_amdgcn_cvt_pk_f32_fp8((int)vy[j],false); av[4]+=w[j]*v[0]; av[5]+=w[j]*v[1];
        v=__builtin_amdgcn_cvt_pk_f32_fp8((int)vy[j],true ); av[6]+=w[j]*v[0]; av[7]+=w[j]*v[1];
      }
    }
  } else {
    // rare fallback (len > 32): strided two-pass with global spill, width-32
    int deg = len-1;
    int lim = mode ? len : deg;
    float lm = -1e30f, e1 = 0.f, e2 = 0.f;
    for(int k=hl;k<lim;k+=32){
      uint2 en = csr[base+k];
      int sr = (int)en.x;
      float lo = bf2f((unsigned short)(en.y & 0xFFFFu));
      float hi = bf2f((unsigned short)(en.y >> 16));
      float etv = mode ? hi : lo;
      if(!mode){ e1 += lo; e2 += hi; }
      float a = asrc[sr] + adi + etv;
      a = fmaxf(a, 0.2f*a);
      alphabuf[base+k]=a; srcbuf[base+k]=sr;
      lm = fmaxf(lm,a);
    }
    #pragma unroll
    for(int mk=16;mk>=1;mk>>=1){
      e1 += __shfl_xor(e1,mk);
      e2 += __shfl_xor(e2,mk);
      lm  = fmaxf(lm, __shfl_xor(lm,mk));
    }
    float aself = 0.f;
    if(!mode){
      float m1 = e1/(float)deg, m2 = e2/(float)deg;
      aself = asrc[i] + adi + m1;
      aself = fmaxf(aself, 0.2f*aself);
      lm = fmaxf(lm, aself);
      if(hl==0){
        uint2 se; se.x=(unsigned)i;
        se.y=(unsigned)f2bf(m1) | ((unsigned)f2bf(m2)<<16);
        csr[base+deg] = se;
      }
    }
    float ls=0.f;
    for(int k=hl;k<len;k+=32){
      float a;
      if(mode) a = alphabuf[base+k];
      else     a = (k<deg)? alphabuf[base+k] : aself;
      float e_ = __expf(a-lm);
      alphabuf[base+k]=e_;
      ls += e_;
    }
    #pragma unroll
    for(int mk=16;mk>=1;mk>>=1) ls += __shfl_xor(ls,mk);
    float inv = 1.f/ls;
    int lim2 = mode ? len : deg;
    int P2 = (len+1)>>1;
    for(int t=0;t<P2;t++){
      int k = 2*t + qq;
      int sk = i; float wk = 0.f;
      if(k<len){
        sk = (k<lim2)? srcbuf[base+k] : i;
        wk = alphabuf[base+k]*inv;
      }
      uint2 u = *(const uint2*)(A8 + (size_t)sk*HH + lq*8);
      f32x2 v;
      v=__builtin_amdgcn_cvt_pk_f32_fp8((int)u.x,false); av[0]+=wk*v[0]; av[1]+=wk*v[1];
      v=__builtin_amdgcn_cvt_pk_f32_fp8((int)u.x,true ); av[2]+=wk*v[0]; av[3]+=wk*v[1];
      v=__builtin_amdgcn_cvt_pk_f32_fp8((int)u.y,false); av[4]+=wk*v[0]; av[5]+=wk*v[1];
      v=__builtin_amdgcn_cvt_pk_f32_fp8((int)u.y,true ); av[6]+=wk*v[0]; av[7]+=wk*v[1];
    }
  }

  // ---- fold the 2 edge sub-slots (xor 16 is half-local) ----
  #pragma unroll
  for(int j=0;j<8;j++) av[j] += __shfl_xor(av[j],16);
  // ---- epilogue: 16 lanes per half store uint4 = full 256B bf16 row ----
  if(qq==0){
    const float4* bp = (const float4*)(bias + lq*8);
    float4 b0=bp[0], b1=bp[1];
    float o0=fmaxf(av[0]+b0.x,0.f), o1=fmaxf(av[1]+b0.y,0.f);
    float o2=fmaxf(av[2]+b0.z,0.f), o3=fmaxf(av[3]+b0.w,0.f);
    float o4=fmaxf(av[4]+b1.x,0.f), o5=fmaxf(av[5]+b1.y,0.f);
    float o6=fmaxf(av[6]+b1.z,0.f), o7=fmaxf(av[7]+b1.w,0.f);
    uint4 ov;
    ov.x=(unsigned)f2bf(o0)|((unsigned)f2bf(o1)<<16);
    ov.y=(unsigned)f2bf(o2)|((unsigned)f2bf(o3)<<16);
    ov.z=(unsigned)f2bf(o4)|((unsigned)f2bf(o5)<<16);
    ov.w=(unsigned)f2bf(o6)|((unsigned)f2bf(o7)<<16);
    *(uint4*)(Bout + (size_t)i*HH + lq*8) = ov;
  }
}

// ---------------- column mean (bf16 input): grid-strided, 512 blocks ----------------
__global__ __launch_bounds__(256) void khg(const unsigned short* __restrict__ B, float* hgsum){
  int f = threadIdx.x & 127;      // column
  int half = threadIdx.x >> 7;    // 0/1
  float s=0.f;
  for(int i = blockIdx.x*2+half; i < NN; i += gridDim.x*2)
    s += bf2f(B[(size_t)i*HH + f]);
  __shared__ float sd[256];
  sd[threadIdx.x]=s; __syncthreads();
  if(half==0) atomicAdd(&hgsum[f], sd[threadIdx.x]+sd[threadIdx.x+128]);
}

// ---------------- tiny decoder, single block ----------------
__global__ __launch_bounds__(256) void kdec(const float* __restrict__ hgsum, const float* __restrict__ eps,
   const float* muW,const float* mub,const float* lvW,const float* lvb,
   const float* decW,const float* decb,
   const float* aW1,const float* ab1,const float* aW2,const float* ab2,
   const float* nW1,const float* nb1,const float* nW2,const float* nb2,
   float* out, float* rowadj, float* rownodes){
  __shared__ float hg[HH], z[LATD], hd[HH], t1[HH], t2[HH];
  int t=threadIdx.x;
  if(t<HH) hg[t]=hgsum[t]*(1.0f/NN);
  __syncthreads();
  if(t<LATD){
    float mu=mub[t], lv=lvb[t];
    #pragma unroll 8
    for(int k=0;k<HH;k++){ mu += hg[k]*muW[k*LATD+t]; lv += hg[k]*lvW[k*LATD+t]; }
    out[MU_OFF+t]=mu; out[LV_OFF+t]=lv;
    z[t]=mu + eps[t]*expf(0.5f*lv);
  }
  __syncthreads();
  if(t<HH){
    float a=decb[t];
    #pragma unroll 8
    for(int k=0;k<LATD;k++) a += z[k]*decW[k*HH+t];
    hd[t]=fmaxf(a,0.f);
  }
  __syncthreads();
  if(t<HH){
    float a=ab1[t];
    #pragma unroll 8
    for(int k=0;k<HH;k++) a += hd[k]*aW1[k*HH+t];
    t1[t]=fmaxf(a,0.f);
  } else {
    int j=t-HH;
    float a=nb1[j];
    #pragma unroll 8
    for(int k=0;k<HH;k++) a += hd[k]*nW1[k*HH+j];
    t2[j]=fmaxf(a,0.f);
  }
  __syncthreads();
  for(int j=t;j<MAXNN;j+=256){
    float a=ab2[j];
    #pragma unroll 8
    for(int k=0;k<HH;k++) a += t1[k]*aW2[k*MAXNN+j];
    rowadj[j]=a;
  }
  if(t<HH){
    float a=nb2[t];
    #pragma unroll 8
    for(int k=0;k<HH;k++) a += t2[k]*nW2[k*HH+t];
    rownodes[t]=a;
  }
}

// ---------------- broadcast: register-resident rows, one output row per wave -------
// lane owns 4 fixed columns (loaded once); a wave stores one contiguous 800B/512B
// row per iteration. Zero LDS -> zero bank conflicts; pure store stream.
__global__ __launch_bounds__(256) void kbcast(const float* __restrict__ rowadj,
                                              const float* __restrict__ rownodes,
                                              float* __restrict__ out){
  int lane = threadIdx.x & 63;
  int wv = (blockIdx.x*256 + threadIdx.x) >> 6;
  int nw = (gridDim.x*256) >> 6;
  float4 aseg = {0.f,0.f,0.f,0.f}, nseg = {0.f,0.f,0.f,0.f};
  if(lane<50) aseg = ((const float4*)rowadj)[lane];
  if(lane<32) nseg = ((const float4*)rownodes)[lane];
  for(int r=wv; r<NN; r+=nw)
    if(lane<50) *(float4*)(out + (size_t)r*MAXNN + lane*4) = aseg;
  for(int r=wv; r<NN; r+=nw)
    if(lane<32) *(float4*)(out + ADJ_TOT + (size_t)r*HH + lane*4) = nseg;
}

extern "C" void kernel_launch(void* const* d_in, const int* in_sizes, int n_in,
                              void* d_out, int out_size, void* d_ws, size_t ws_size,
                              hipStream_t stream){
  const float* x   = (const float*)d_in[0];
  const int*   ei  = (const int*)d_in[1];
  const float* ea  = (const float*)d_in[2];
  const float* eps = (const float*)d_in[3];
  const float* W1  =(const float*)d_in[5];
  const float* as1 =(const float*)d_in[6];
  const float* ad1 =(const float*)d_in[7];
  const float* We1 =(const float*)d_in[8];
  const float* ae1 =(const float*)d_in[9];
  const float* b1  =(const float*)d_in[10];
  const float* W2  =(const float*)d_in[11];
  const float* as2 =(const float*)d_in[12];
  const float* ad2 =(const float*)d_in[13];
  const float* We2 =(const float*)d_in[14];
  const float* ae2 =(const float*)d_in[15];
  const float* b2  =(const float*)d_in[16];
  const float* muW =(const float*)d_in[17];
  const float* mub =(const float*)d_in[18];
  const float* lvW =(const float*)d_in[19];
  const float* lvb =(const float*)d_in[20];
  const float* decW=(const float*)d_in[21];
  const float* decb=(const float*)d_in[22];
  const float* aW1 =(const float*)d_in[23];
  const float* ab1 =(const float*)d_in[24];
  const float* aW2 =(const float*)d_in[25];
  const float* ab2 =(const float*)d_in[26];
  const float* nW1 =(const float*)d_in[27];
  const float* nb1 =(const float*)d_in[28];
  const float* nW2 =(const float*)d_in[29];
  const float* nb2 =(const float*)d_in[30];
  float* out=(float*)d_out;

  char* w=(char*)d_ws;
  unsigned char*  A8  = (unsigned char*)w;  w += (size_t)NN*HH;      // 6.4 MB fp8
  unsigned short* Bbf = (unsigned short*)w; w += (size_t)NN*HH*2;    // 12.8 MB bf16
  unsigned short* Wp1 = (unsigned short*)w; w += (size_t)HH*HH*2;
  unsigned short* Wp2 = (unsigned short*)w; w += (size_t)HH*HH*2;
  uint2*  csr      = (uint2*)w;  w += (size_t)EF*8;                  // 6.8 MB
  float*  alphabuf = (float*)w;  w += (size_t)EF*4;
  int*    srcbuf   = (int*)w;    w += (size_t)EF*4;
  unsigned* ety    = (unsigned*)w; w += (size_t)EE*4;                // 3.2 MB
  unsigned short* erank = (unsigned short*)w; w += (size_t)EE*2;
  int*    rowstart = (int*)w;    w += (size_t)(NN+1)*4;
  int*    ideg     = (int*)w;    w += (size_t)NN*4;
  float*  hgsum    = (float*)w;  w += 128*4;
  float*  asrc     = (float*)w;  w += (size_t)NN*4;
  float*  adst     = (float*)w;  w += (size_t)NN*4;
  float*  wa1      = (float*)w;  w += 16*4;
  float*  wa2      = (float*)w;  w += 16*4;
  float*  rowadj   = (float*)w;  w += 256*4;
  float*  rownodes = (float*)w;  w += 128*4;
  unsigned* scanpub= (unsigned*)w; w += 64*4;

  int gatblocks  = (NN+7)/8;     // 6250 (2 nodes per wave, 8 per block)

  hipLaunchKernelGGL(kprep, dim3((NN+255)/256), dim3(256), 0, stream,
                     ideg, hgsum, scanpub, We1, ae1, We2, ae2, wa1, wa2, W1, W2, Wp1, Wp2);
  // gemm L1 overlapped with degree atomics + intra-thread edge-attr pack
  hipLaunchKernelGGL(kdeggemm, dim3(GEMMBLOCKS+DEGBLOCKS), dim3(256), 0, stream,
                     ei, ideg, erank, ea, wa1, wa2, ety,
                     (const void*)x, 1, Wp1, as1, ad1, A8, asrc, adst);
  hipLaunchKernelGGL(kscanf, dim3(NBSCAN), dim3(1024), 0, stream, ideg, rowstart, scanpub);
  hipLaunchKernelGGL(kscatter, dim3((EE/4+255)/256), dim3(256), 0, stream,
                     ei, ety, rowstart, erank, csr);
  // layer 1 aggregate (mode 0: computes + stores self entries)
  hipLaunchKernelGGL(kgat,  dim3(gatblocks), dim3(256), 0, stream,
                     A8, asrc, adst, rowstart, csr, 0, b1, alphabuf, srcbuf, Bbf);
  // layer 2 (bf16 input)
  hipLaunchKernelGGL(kgemm3, dim3(GEMMBLOCKS), dim3(256), 0, stream,
                     (const void*)Bbf, 0, Wp2, as2, ad2, A8, asrc, adst);
  // layer 2 aggregate (mode 1: uniform csr read, no ets chain)
  hipLaunchKernelGGL(kgat,  dim3(gatblocks), dim3(256), 0, stream,
                     A8, asrc, adst, rowstart, csr, 1, b2, alphabuf, srcbuf, Bbf);
  // graph embedding + decoder + broadcast
  hipLaunchKernelGGL(khg,   dim3(512), dim3(256), 0, stream, Bbf, hgsum);
  hipLaunchKernelGGL(kdec,  dim3(1), dim3(256), 0, stream, hgsum, eps,
                     muW,mub,lvW,lvb,decW,decb,aW1,ab1,aW2,ab2,nW1,nb1,nW2,nb2,
                     out, rowadj, rownodes);
  hipLaunchKernelGGL(kbcast, dim3(2048), dim3(256), 0, stream, rowadj, rownodes, out);
}